// Round 1
// baseline (3863.640 us; speedup 1.0000x reference)
//
#include <hip/hip_runtime.h>

#define D 128

// ---------------- CSR build ----------------

__global__ void hist_kernel(const int* __restrict__ dst, int* __restrict__ counts, int E) {
  int stride = gridDim.x * blockDim.x;
  for (int e = blockIdx.x * blockDim.x + threadIdx.x; e < E; e += stride)
    atomicAdd(&counts[dst[e]], 1);
}

__global__ void dis_kernel(const int* __restrict__ counts, float* __restrict__ dis, int N) {
  int n = blockIdx.x * blockDim.x + threadIdx.x;
  if (n < N) dis[n] = rsqrtf((float)counts[n] + 1.0f);
}

// single-block exclusive scan over counts -> row_ptr, fill
__global__ __launch_bounds__(1024) void scan_kernel(const int* __restrict__ counts,
    int* __restrict__ row_ptr, int* __restrict__ fillp, int N) {
  __shared__ int sa[1024];
  __shared__ int sb[1024];
  int t = threadIdx.x;
  int offset = 0;
  int nch = (N + 1023) >> 10;
  for (int c = 0; c < nch; ++c) {
    int idx = (c << 10) + t;
    int v = (idx < N) ? counts[idx] : 0;
    sa[t] = v;
    __syncthreads();
    int* a = sa; int* b = sb;
    #pragma unroll
    for (int d = 1; d < 1024; d <<= 1) {
      int val = a[t] + ((t >= d) ? a[t - d] : 0);
      b[t] = val;
      __syncthreads();
      int* tmp = a; a = b; b = tmp;
    }
    int incl = a[t];
    int total = a[1023];
    if (idx < N) {
      int excl = offset + incl - v;
      row_ptr[idx] = excl;
      fillp[idx] = excl;
    }
    offset += total;
    __syncthreads();
  }
  if (t == 0) row_ptr[N] = offset;
}

__global__ void fill_kernel(const int* __restrict__ src, const int* __restrict__ dst,
    const float* __restrict__ dis, int* __restrict__ fillp, int* __restrict__ csr_src,
    float* __restrict__ csr_w, int E) {
  int stride = gridDim.x * blockDim.x;
  for (int e = blockIdx.x * blockDim.x + threadIdx.x; e < E; e += stride) {
    int s = src[e], d = dst[e];
    int p = atomicAdd(&fillp[d], 1);
    csr_src[p] = s;
    csr_w[p] = dis[s];   // dis[dst] factored out, applied in agg epilogue
  }
}

// ---------------- GEMM: O = H @ W  (fp32, W in LDS) ----------------

__global__ __launch_bounds__(256) void gemm_kernel(const float* __restrict__ H,
    const float* __restrict__ W, float* __restrict__ O, int N) {
  __shared__ float sW[128 * 128];   // 64 KB
  __shared__ float sH[64 * 36];     // 9 KB (stride 36 to break bank conflicts)
  int tid = threadIdx.x;
  #pragma unroll
  for (int i = 0; i < 16; ++i) {
    int idx = (i * 256 + tid) * 4;
    *(float4*)&sW[idx] = *(const float4*)&W[idx];
  }
  int row_base = blockIdx.x * 64;
  int rg = tid >> 4;        // 0..15 row group (4 rows each)
  int cg = tid & 15;        // 0..15 col group (8 cols each)
  int col0 = cg * 8;
  float acc[4][8];
  #pragma unroll
  for (int r = 0; r < 4; ++r)
    #pragma unroll
    for (int c = 0; c < 8; ++c) acc[r][c] = 0.f;

  for (int kb = 0; kb < 4; ++kb) {
    __syncthreads();
    // stage h[64][32] for this K-chunk
    for (int i = tid; i < 64 * 8; i += 256) {
      int r = i >> 3;
      int kq = i & 7;
      int gr = row_base + r;
      float4 v = make_float4(0.f, 0.f, 0.f, 0.f);
      if (gr < N) v = *(const float4*)&H[(size_t)gr * D + kb * 32 + kq * 4];
      *(float4*)&sH[r * 36 + kq * 4] = v;
    }
    __syncthreads();
    #pragma unroll
    for (int kk = 0; kk < 32; ++kk) {
      int k = kb * 32 + kk;
      float wv[8];
      *(float4*)&wv[0] = *(float4*)&sW[k * 128 + col0];
      *(float4*)&wv[4] = *(float4*)&sW[k * 128 + col0 + 4];
      #pragma unroll
      for (int r = 0; r < 4; ++r) {
        float hv = sH[(rg * 4 + r) * 36 + kk];
        #pragma unroll
        for (int c = 0; c < 8; ++c) acc[r][c] += hv * wv[c];
      }
    }
  }
  #pragma unroll
  for (int r = 0; r < 4; ++r) {
    int gr = row_base + rg * 4 + r;
    if (gr < N) {
      *(float4*)&O[(size_t)gr * D + col0] =
          make_float4(acc[r][0], acc[r][1], acc[r][2], acc[r][3]);
      *(float4*)&O[(size_t)gr * D + col0 + 4] =
          make_float4(acc[r][4], acc[r][5], acc[r][6], acc[r][7]);
    }
  }
}

// ---------------- Aggregate + fused epilogue ----------------
// val = dis[n] * sum_e(csr_w[e] * hw[src_e]) + hw[n]*dis[n]^2 + b
// flags: 1 = add init_in, 2 = write init_out, 4 = relu, 8 = hout += val
__global__ __launch_bounds__(256) void agg_kernel(const float* __restrict__ hw,
    const int* __restrict__ row_ptr, const int* __restrict__ csr_src,
    const float* __restrict__ csr_w, const float* __restrict__ dis,
    const float* __restrict__ bias, const float* __restrict__ init_in,
    float* __restrict__ init_out, float* __restrict__ hout, int N, int flags) {
  int wave = blockIdx.x * 4 + (threadIdx.x >> 6);
  int lane = threadIdx.x & 63;
  if (wave >= N) return;
  int n = wave;
  int beg = row_ptr[n], end = row_ptr[n + 1];
  int c0 = lane * 2;
  float ax = 0.f, ay = 0.f;
  for (int e = beg; e < end; ++e) {
    int s = csr_src[e];
    float w = csr_w[e];
    float2 v = *(const float2*)&hw[(size_t)s * D + c0];
    ax += w * v.x;
    ay += w * v.y;
  }
  float dn = dis[n];
  float sn = dn * dn;
  float2 hv = *(const float2*)&hw[(size_t)n * D + c0];
  float2 bv = *(const float2*)&bias[c0];
  float vx = dn * ax + hv.x * sn + bv.x;
  float vy = dn * ay + hv.y * sn + bv.y;
  if (flags & 1) {
    float2 iv = *(const float2*)&init_in[(size_t)n * D + c0];
    vx += iv.x; vy += iv.y;
  }
  if (flags & 2) {
    *(float2*)&init_out[(size_t)n * D + c0] = make_float2(vx, vy);
  }
  if (flags & 4) {
    vx = fmaxf(vx, 0.f); vy = fmaxf(vy, 0.f);
  }
  if (flags & 8) {
    float2 pv = *(const float2*)&hout[(size_t)n * D + c0];
    vx += pv.x; vy += pv.y;
  }
  *(float2*)&hout[(size_t)n * D + c0] = make_float2(vx, vy);
}

// ---------------- launch ----------------

extern "C" void kernel_launch(void* const* d_in, const int* in_sizes, int n_in,
                              void* d_out, int out_size, void* d_ws, size_t ws_size,
                              hipStream_t stream) {
  const float* x = (const float*)d_in[0];
  const int* ei = (const int*)d_in[1];
  const float* Ws = (const float*)d_in[2];
  const float* bs = (const float*)d_in[3];
  float* out = (float*)d_out;

  const int N = in_sizes[0] / D;
  const int E = in_sizes[1] / 2;
  const int L = in_sizes[2] / (D * D);
  const int* src = ei;
  const int* dst = ei + E;

  uintptr_t p = (uintptr_t)d_ws;
  auto alloc = [&](size_t bytes) {
    uintptr_t r = p;
    p = (r + bytes + 255) & ~(uintptr_t)255;
    return r;
  };
  float* dis     = (float*)alloc((size_t)N * 4);
  int*   counts  = (int*)  alloc((size_t)N * 4);
  int*   row_ptr = (int*)  alloc((size_t)(N + 1) * 4);
  int*   fillp   = (int*)  alloc((size_t)N * 4);
  int*   csr_src = (int*)  alloc((size_t)E * 4);
  float* csr_w   = (float*)alloc((size_t)E * 4);
  float* hw      = (float*)alloc((size_t)N * D * 4);
  float* init_buf= (float*)alloc((size_t)N * D * 4);

  hipMemsetAsync(counts, 0, (size_t)N * 4, stream);
  hist_kernel<<<1024, 256, 0, stream>>>(dst, counts, E);
  dis_kernel<<<(N + 255) / 256, 256, 0, stream>>>(counts, dis, N);
  scan_kernel<<<1, 1024, 0, stream>>>(counts, row_ptr, fillp, N);
  fill_kernel<<<1024, 256, 0, stream>>>(src, dst, dis, fillp, csr_src, csr_w, E);

  const int agg_grid = (N + 3) / 4;
  const int gemm_grid = (N + 63) / 64;

  const float* h = x;
  for (int i = 0; i < L; ++i) {
    gemm_kernel<<<gemm_grid, 256, 0, stream>>>(h, Ws + (size_t)i * D * D, hw, N);
    int flags = (i == 0) ? 4 : (1 | 2 | 4);
    const float* init_in = (i <= 1) ? x : (const float*)init_buf;
    agg_kernel<<<agg_grid, 256, 0, stream>>>(hw, row_ptr, csr_src, csr_w, dis,
        bs + (size_t)i * D, init_in, init_buf, out, N, flags);
    h = out;
    if (i < L - 1) {
      int j = (i == 0) ? (L - 1) : (i - 1);
      gemm_kernel<<<gemm_grid, 256, 0, stream>>>(h, Ws + (size_t)j * D * D, hw, N);
      agg_kernel<<<agg_grid, 256, 0, stream>>>(hw, row_ptr, csr_src, csr_w, dis,
          bs + (size_t)j * D, nullptr, nullptr, out, N, 8);
    }
  }
}

// Round 2
// 1710.949 us; speedup vs baseline: 2.2582x; 2.2582x over previous
//
#include <hip/hip_runtime.h>

#define D 128

typedef _Float16 f16x8 __attribute__((ext_vector_type(8)));
typedef _Float16 f16x4 __attribute__((ext_vector_type(4)));
typedef float f32x4 __attribute__((ext_vector_type(4)));

// ---------------- CSR build ----------------

__global__ void hist_kernel(const int* __restrict__ dst, int* __restrict__ counts, int E) {
  int stride = gridDim.x * blockDim.x;
  for (int e = blockIdx.x * blockDim.x + threadIdx.x; e < E; e += stride)
    atomicAdd(&counts[dst[e]], 1);
}

__global__ void dis_kernel(const int* __restrict__ counts, float* __restrict__ dis, int N) {
  int n = blockIdx.x * blockDim.x + threadIdx.x;
  if (n < N) dis[n] = rsqrtf((float)counts[n] + 1.0f);
}

__global__ __launch_bounds__(1024) void scan_kernel(const int* __restrict__ counts,
    int* __restrict__ row_ptr, int* __restrict__ fillp, int N) {
  __shared__ int sa[1024];
  __shared__ int sb[1024];
  int t = threadIdx.x;
  int offset = 0;
  int nch = (N + 1023) >> 10;
  for (int c = 0; c < nch; ++c) {
    int idx = (c << 10) + t;
    int v = (idx < N) ? counts[idx] : 0;
    sa[t] = v;
    __syncthreads();
    int* a = sa; int* b = sb;
    #pragma unroll
    for (int d = 1; d < 1024; d <<= 1) {
      int val = a[t] + ((t >= d) ? a[t - d] : 0);
      b[t] = val;
      __syncthreads();
      int* tmp = a; a = b; b = tmp;
    }
    int incl = a[t];
    int total = a[1023];
    if (idx < N) {
      int excl = offset + incl - v;
      row_ptr[idx] = excl;
      fillp[idx] = excl;
    }
    offset += total;
    __syncthreads();
  }
  if (t == 0) row_ptr[N] = offset;
}

__global__ void fill_kernel(const int* __restrict__ src, const int* __restrict__ dst,
    const float* __restrict__ dis, int* __restrict__ fillp, int2* __restrict__ csr, int E) {
  int stride = gridDim.x * blockDim.x;
  for (int e = blockIdx.x * blockDim.x + threadIdx.x; e < E; e += stride) {
    int s = src[e], d = dst[e];
    int p = atomicAdd(&fillp[d], 1);
    csr[p] = make_int2(s, __float_as_int(dis[s]));
  }
}

// ---------------- one-time conversions ----------------

__global__ void conv_x_kernel(const float* __restrict__ x, _Float16* __restrict__ x16, int total8) {
  int i = blockIdx.x * blockDim.x + threadIdx.x;
  if (i >= total8) return;
  const float4* p = (const float4*)(x + (size_t)i * 8);
  float4 a = p[0], b = p[1];
  f16x8 v;
  v[0] = (_Float16)a.x; v[1] = (_Float16)a.y; v[2] = (_Float16)a.z; v[3] = (_Float16)a.w;
  v[4] = (_Float16)b.x; v[5] = (_Float16)b.y; v[6] = (_Float16)b.z; v[7] = (_Float16)b.w;
  *(f16x8*)(x16 + (size_t)i * 8) = v;
}

// Wf layout: [L][kb(4)][nb(8)][lane(64)] of f16x8 (B fragment, K-slice 8)
__global__ void repack_w_kernel(const float* __restrict__ Ws, _Float16* __restrict__ Wf, int total) {
  int t = blockIdx.x * blockDim.x + threadIdx.x;
  if (t >= total) return;
  int lane = t & 63;
  int nb = (t >> 6) & 7;
  int kb = (t >> 9) & 3;
  int l = t >> 11;
  int col = nb * 16 + (lane & 15);
  int k0 = kb * 32 + (lane >> 4) * 8;
  const float* w = Ws + (size_t)l * D * D;
  f16x8 v;
  #pragma unroll
  for (int j = 0; j < 8; ++j) v[j] = (_Float16)w[(k0 + j) * D + col];
  *(f16x8*)(Wf + (size_t)t * 8) = v;
}

// ---------------- GEMM: O16 = H16 @ W (fp16 MFMA, fp32 accum) ----------------

__global__ __launch_bounds__(256) void gemm16_kernel(const _Float16* __restrict__ H,
    const f16x8* __restrict__ Wf, _Float16* __restrict__ O, int N) {
  __shared__ _Float16 sC[4][16 * 128];
  int wave = threadIdx.x >> 6;
  int lane = threadIdx.x & 63;
  int row0 = blockIdx.x * 64 + wave * 16;
  int arow = row0 + (lane & 15);
  if (arow >= N) arow = N - 1;
  const _Float16* aptr = H + (size_t)arow * D + (lane >> 4) * 8;
  f32x4 acc[8];
  #pragma unroll
  for (int nb = 0; nb < 8; ++nb) acc[nb] = (f32x4){0.f, 0.f, 0.f, 0.f};

  #pragma unroll
  for (int kb = 0; kb < 4; ++kb) {
    f16x8 a = *(const f16x8*)(aptr + kb * 32);
    #pragma unroll
    for (int nb = 0; nb < 8; ++nb) {
      f16x8 b = Wf[(kb * 8 + nb) * 64 + lane];
      acc[nb] = __builtin_amdgcn_mfma_f32_16x16x32_f16(a, b, acc[nb], 0, 0, 0);
    }
  }
  // stage C to LDS (2B writes), then coalesced 16B global stores
  #pragma unroll
  for (int nb = 0; nb < 8; ++nb)
    #pragma unroll
    for (int r = 0; r < 4; ++r) {
      int row = (lane >> 4) * 4 + r;
      int col = nb * 16 + (lane & 15);
      sC[wave][row * 128 + col] = (_Float16)acc[nb][r];
    }
  __syncthreads();
  #pragma unroll
  for (int it = 0; it < 4; ++it) {
    int r = it * 4 + (lane >> 4);
    int gr = row0 + r;
    if (gr < N)
      *(f16x8*)&O[(size_t)gr * D + (lane & 15) * 8] =
          *(const f16x8*)&sC[wave][r * 128 + (lane & 15) * 8];
  }
}

// ---------------- Aggregate + fused epilogue ----------------
// val = dis[n]*sum_e(w_e*hw16[src_e]) + hw16[n]*dis[n]^2 + b
// flags: 1=add init_in, 2=write init_out, 4=relu, 8=out += val, 16=write h16
__global__ __launch_bounds__(256) void agg16_kernel(const _Float16* __restrict__ hw,
    const int* __restrict__ row_ptr, const int2* __restrict__ csr,
    const float* __restrict__ dis, const float* __restrict__ bias,
    const float* __restrict__ init_in, float* __restrict__ init_out,
    float* __restrict__ out, _Float16* __restrict__ h16, int N, int flags) {
  int n = (blockIdx.x * 256 + threadIdx.x) >> 5;   // one node per 32-lane half-wave
  int li = threadIdx.x & 31;
  if (n >= N) return;
  int beg = row_ptr[n], end = row_ptr[n + 1];
  int c0 = li * 4;
  float a0 = 0.f, a1 = 0.f, a2 = 0.f, a3 = 0.f;
  #pragma unroll 4
  for (int e = beg; e < end; ++e) {
    int2 ew = csr[e];
    float w = __int_as_float(ew.y);
    f16x4 v = *(const f16x4*)&hw[(size_t)ew.x * D + c0];
    a0 += w * (float)v[0];
    a1 += w * (float)v[1];
    a2 += w * (float)v[2];
    a3 += w * (float)v[3];
  }
  float dn = dis[n];
  float sn = dn * dn;
  f16x4 hv = *(const f16x4*)&hw[(size_t)n * D + c0];
  float4 bv = *(const float4*)&bias[c0];
  float v0 = dn * a0 + (float)hv[0] * sn + bv.x;
  float v1 = dn * a1 + (float)hv[1] * sn + bv.y;
  float v2 = dn * a2 + (float)hv[2] * sn + bv.z;
  float v3 = dn * a3 + (float)hv[3] * sn + bv.w;
  size_t off = (size_t)n * D + c0;
  if (flags & 1) {
    float4 iv = *(const float4*)&init_in[off];
    v0 += iv.x; v1 += iv.y; v2 += iv.z; v3 += iv.w;
  }
  if (flags & 2)
    *(float4*)&init_out[off] = make_float4(v0, v1, v2, v3);
  if (flags & 4) {
    v0 = fmaxf(v0, 0.f); v1 = fmaxf(v1, 0.f);
    v2 = fmaxf(v2, 0.f); v3 = fmaxf(v3, 0.f);
  }
  if (flags & 8) {
    float4 pv = *(const float4*)&out[off];
    v0 += pv.x; v1 += pv.y; v2 += pv.z; v3 += pv.w;
  }
  *(float4*)&out[off] = make_float4(v0, v1, v2, v3);
  if (flags & 16) {
    f16x4 hw4;
    hw4[0] = (_Float16)v0; hw4[1] = (_Float16)v1;
    hw4[2] = (_Float16)v2; hw4[3] = (_Float16)v3;
    *(f16x4*)&h16[off] = hw4;
  }
}

// ---------------- launch ----------------

extern "C" void kernel_launch(void* const* d_in, const int* in_sizes, int n_in,
                              void* d_out, int out_size, void* d_ws, size_t ws_size,
                              hipStream_t stream) {
  const float* x = (const float*)d_in[0];
  const int* ei = (const int*)d_in[1];
  const float* Ws = (const float*)d_in[2];
  const float* bs = (const float*)d_in[3];
  float* out = (float*)d_out;

  const int N = in_sizes[0] / D;
  const int E = in_sizes[1] / 2;
  const int L = in_sizes[2] / (D * D);
  const int* src = ei;
  const int* dst = ei + E;

  uintptr_t p = (uintptr_t)d_ws;
  auto alloc = [&](size_t bytes) {
    uintptr_t r = p;
    p = (r + bytes + 255) & ~(uintptr_t)255;
    return r;
  };
  float*     dis      = (float*)alloc((size_t)N * 4);
  int*       counts   = (int*)  alloc((size_t)N * 4);
  int*       row_ptr  = (int*)  alloc((size_t)(N + 1) * 4);
  int*       fillp    = (int*)  alloc((size_t)N * 4);
  int2*      csr      = (int2*) alloc((size_t)E * 8);
  _Float16*  hw16     = (_Float16*)alloc((size_t)N * D * 2);
  _Float16*  h16      = (_Float16*)alloc((size_t)N * D * 2);  // also holds x16
  float*     init_buf = (float*)alloc((size_t)N * D * 4);
  _Float16*  Wf       = (_Float16*)alloc((size_t)L * 4 * 8 * 64 * 8 * 2);

  hipMemsetAsync(counts, 0, (size_t)N * 4, stream);
  hist_kernel<<<1024, 256, 0, stream>>>(dst, counts, E);
  dis_kernel<<<(N + 255) / 256, 256, 0, stream>>>(counts, dis, N);
  scan_kernel<<<1, 1024, 0, stream>>>(counts, row_ptr, fillp, N);
  fill_kernel<<<1024, 256, 0, stream>>>(src, dst, dis, fillp, csr, E);
  conv_x_kernel<<<(N * D / 8 + 255) / 256, 256, 0, stream>>>(x, h16, N * D / 8);
  {
    int total = L * 2048;
    repack_w_kernel<<<(total + 255) / 256, 256, 0, stream>>>(Ws, Wf, total);
  }

  const int agg_grid = (N + 7) / 8;
  const int gemm_grid = (N + 63) / 64;

  for (int i = 0; i < L; ++i) {
    gemm16_kernel<<<gemm_grid, 256, 0, stream>>>(
        h16, (const f16x8*)(Wf + (size_t)i * 2048 * 8), hw16, N);
    int flags;
    if (i == 0)          flags = 4 | 16;
    else if (i == L - 1) flags = 1 | 4;           // final output: no init/h16 writes needed
    else                 flags = 1 | 2 | 4 | 16;
    const float* init_in = (i <= 1) ? x : (const float*)init_buf;
    agg16_kernel<<<agg_grid, 256, 0, stream>>>(hw16, row_ptr, csr, dis,
        bs + (size_t)i * D, init_in, init_buf, out, h16, N, flags);
    if (i < L - 1) {
      int j = (i == 0) ? (L - 1) : (i - 1);
      gemm16_kernel<<<gemm_grid, 256, 0, stream>>>(
          h16, (const f16x8*)(Wf + (size_t)j * 2048 * 8), hw16, N);
      agg16_kernel<<<agg_grid, 256, 0, stream>>>(hw16, row_ptr, csr, dis,
          bs + (size_t)j * D, nullptr, nullptr, out, h16, N, 8 | 16);
    }
  }
}

// Round 3
// 1605.920 us; speedup vs baseline: 2.4059x; 1.0654x over previous
//
#include <hip/hip_runtime.h>

#define D 128
#define SCAN_CH 1024

typedef _Float16 f16x8 __attribute__((ext_vector_type(8)));
typedef _Float16 f16x4 __attribute__((ext_vector_type(4)));
typedef float f32x4 __attribute__((ext_vector_type(4)));

// ---------------- CSR build ----------------

__global__ void hist_kernel(const int* __restrict__ dst, int* __restrict__ counts, int E) {
  int stride = gridDim.x * blockDim.x;
  for (int e = blockIdx.x * blockDim.x + threadIdx.x; e < E; e += stride)
    atomicAdd(&counts[dst[e]], 1);
}

__global__ void dis_kernel(const int* __restrict__ counts, float* __restrict__ dis, int N) {
  int n = blockIdx.x * blockDim.x + threadIdx.x;
  if (n < N) dis[n] = rsqrtf((float)counts[n] + 1.0f);
}

// 3-phase scan: A = per-block sums, B = scan of block sums, C = local scan + offset
__global__ __launch_bounds__(256) void scan_phaseA(const int* __restrict__ counts,
    int* __restrict__ blksum, int N) {
  __shared__ int red[256];
  int base = blockIdx.x * SCAN_CH;
  int t = threadIdx.x;
  int s = 0;
  #pragma unroll
  for (int j = 0; j < 4; ++j) {
    int idx = base + t * 4 + j;
    if (idx < N) s += counts[idx];
  }
  red[t] = s;
  __syncthreads();
  for (int d = 128; d > 0; d >>= 1) {
    if (t < d) red[t] += red[t + d];
    __syncthreads();
  }
  if (t == 0) blksum[blockIdx.x] = red[0];
}

__global__ __launch_bounds__(1024) void scan_phaseB(int* __restrict__ blksum, int NB) {
  __shared__ int sa[1024], sb[1024];
  int t = threadIdx.x;
  int v = (t < NB) ? blksum[t] : 0;
  sa[t] = v;
  __syncthreads();
  int* a = sa; int* b = sb;
  for (int d = 1; d < 1024; d <<= 1) {
    int val = a[t] + ((t >= d) ? a[t - d] : 0);
    b[t] = val;
    __syncthreads();
    int* tmp = a; a = b; b = tmp;
  }
  if (t < NB) blksum[t] = a[t] - v;  // exclusive
}

__global__ __launch_bounds__(256) void scan_phaseC(const int* __restrict__ counts,
    const int* __restrict__ blksum, int* __restrict__ row_ptr, int* __restrict__ fillp, int N) {
  __shared__ int ra[256], rb[256];
  int base = blockIdx.x * SCAN_CH;
  int t = threadIdx.x;
  int v[4]; int s = 0;
  #pragma unroll
  for (int j = 0; j < 4; ++j) {
    int idx = base + t * 4 + j;
    v[j] = (idx < N) ? counts[idx] : 0;
    s += v[j];
  }
  ra[t] = s;
  __syncthreads();
  int* a = ra; int* b = rb;
  for (int d = 1; d < 256; d <<= 1) {
    int val = a[t] + ((t >= d) ? a[t - d] : 0);
    b[t] = val;
    __syncthreads();
    int* tmp = a; a = b; b = tmp;
  }
  int excl = a[t] - s + blksum[blockIdx.x];
  #pragma unroll
  for (int j = 0; j < 4; ++j) {
    int idx = base + t * 4 + j;
    if (idx < N) {
      row_ptr[idx] = excl;
      fillp[idx] = excl;
      excl += v[j];
      if (idx == N - 1) row_ptr[N] = excl;
    }
  }
}

__global__ void fill_kernel(const int* __restrict__ src, const int* __restrict__ dst,
    const float* __restrict__ dis, int* __restrict__ fillp, int2* __restrict__ csr, int E) {
  int stride = gridDim.x * blockDim.x;
  for (int e = blockIdx.x * blockDim.x + threadIdx.x; e < E; e += stride) {
    int s = src[e], d = dst[e];
    int p = atomicAdd(&fillp[d], 1);
    csr[p] = make_int2(s, __float_as_int(dis[s]));
  }
}

// ---------------- one-time conversions ----------------

__global__ void conv_x_kernel(const float* __restrict__ x, _Float16* __restrict__ x16, int total8) {
  int i = blockIdx.x * blockDim.x + threadIdx.x;
  if (i >= total8) return;
  const float4* p = (const float4*)(x + (size_t)i * 8);
  float4 a = p[0], b = p[1];
  f16x8 v;
  v[0] = (_Float16)a.x; v[1] = (_Float16)a.y; v[2] = (_Float16)a.z; v[3] = (_Float16)a.w;
  v[4] = (_Float16)b.x; v[5] = (_Float16)b.y; v[6] = (_Float16)b.z; v[7] = (_Float16)b.w;
  *(f16x8*)(x16 + (size_t)i * 8) = v;
}

// Wf layout: [L][kb(4)][nb(8)][lane(64)] of f16x8 (B fragment, K-slice 8)
__global__ void repack_w_kernel(const float* __restrict__ Ws, _Float16* __restrict__ Wf, int total) {
  int t = blockIdx.x * blockDim.x + threadIdx.x;
  if (t >= total) return;
  int lane = t & 63;
  int nb = (t >> 6) & 7;
  int kb = (t >> 9) & 3;
  int l = t >> 11;
  int col = nb * 16 + (lane & 15);
  int k0 = kb * 32 + (lane >> 4) * 8;
  const float* w = Ws + (size_t)l * D * D;
  f16x8 v;
  #pragma unroll
  for (int j = 0; j < 8; ++j) v[j] = (_Float16)w[(k0 + j) * D + col];
  *(f16x8*)(Wf + (size_t)t * 8) = v;
}

// ---------------- GEMM: O16 = H16 @ W (fp16 MFMA, fp32 accum) ----------------

__global__ __launch_bounds__(256) void gemm16_kernel(const _Float16* __restrict__ H,
    const f16x8* __restrict__ Wf, _Float16* __restrict__ O, int N) {
  __shared__ _Float16 sC[4][16 * 128];
  int wave = threadIdx.x >> 6;
  int lane = threadIdx.x & 63;
  int row0 = blockIdx.x * 64 + wave * 16;
  int arow = row0 + (lane & 15);
  if (arow >= N) arow = N - 1;
  const _Float16* aptr = H + (size_t)arow * D + (lane >> 4) * 8;
  f32x4 acc[8];
  #pragma unroll
  for (int nb = 0; nb < 8; ++nb) acc[nb] = (f32x4){0.f, 0.f, 0.f, 0.f};

  #pragma unroll
  for (int kb = 0; kb < 4; ++kb) {
    f16x8 a = *(const f16x8*)(aptr + kb * 32);
    #pragma unroll
    for (int nb = 0; nb < 8; ++nb) {
      f16x8 b = Wf[(kb * 8 + nb) * 64 + lane];
      acc[nb] = __builtin_amdgcn_mfma_f32_16x16x32_f16(a, b, acc[nb], 0, 0, 0);
    }
  }
  #pragma unroll
  for (int nb = 0; nb < 8; ++nb)
    #pragma unroll
    for (int r = 0; r < 4; ++r) {
      int row = (lane >> 4) * 4 + r;
      int col = nb * 16 + (lane & 15);
      sC[wave][row * 128 + col] = (_Float16)acc[nb][r];
    }
  __syncthreads();
  #pragma unroll
  for (int it = 0; it < 4; ++it) {
    int r = it * 4 + (lane >> 4);
    int gr = row0 + r;
    if (gr < N)
      *(f16x8*)&O[(size_t)gr * D + (lane & 15) * 8] =
          *(const f16x8*)&sC[wave][r * 128 + (lane & 15) * 8];
  }
}

// ---------------- Aggregate + fused epilogue ----------------
// One node per 16-lane group (f16x8 per lane = full 256B row per group).
// val = dis[n]*sum_e(w_e*hw16[src_e]) + hw16[n]*dis[n]^2 + b
// flags: 1=add init_in, 2=write init_out, 4=relu, 8=out += val, 16=write h16
__global__ __launch_bounds__(256) void agg16_kernel(const _Float16* __restrict__ hw,
    const int* __restrict__ row_ptr, const int2* __restrict__ csr,
    const float* __restrict__ dis, const float* __restrict__ bias,
    const float* __restrict__ init_in, float* __restrict__ init_out,
    float* __restrict__ out, _Float16* __restrict__ h16, int N, int flags) {
  int n = (blockIdx.x * 256 + threadIdx.x) >> 4;   // one node per 16-lane group
  int li = threadIdx.x & 15;
  if (n >= N) return;
  int beg = row_ptr[n], end = row_ptr[n + 1];
  int c0 = li * 8;
  float acc[8];
  #pragma unroll
  for (int j = 0; j < 8; ++j) acc[j] = 0.f;
  #pragma unroll 4
  for (int e = beg; e < end; ++e) {
    int2 ew = csr[e];
    float w = __int_as_float(ew.y);
    f16x8 v = *(const f16x8*)&hw[(size_t)ew.x * D + c0];
    #pragma unroll
    for (int j = 0; j < 8; ++j) acc[j] += w * (float)v[j];
  }
  float dn = dis[n];
  float sn = dn * dn;
  f16x8 hv = *(const f16x8*)&hw[(size_t)n * D + c0];
  float4 b0 = *(const float4*)&bias[c0];
  float4 b1 = *(const float4*)&bias[c0 + 4];
  float v[8];
  v[0] = dn * acc[0] + (float)hv[0] * sn + b0.x;
  v[1] = dn * acc[1] + (float)hv[1] * sn + b0.y;
  v[2] = dn * acc[2] + (float)hv[2] * sn + b0.z;
  v[3] = dn * acc[3] + (float)hv[3] * sn + b0.w;
  v[4] = dn * acc[4] + (float)hv[4] * sn + b1.x;
  v[5] = dn * acc[5] + (float)hv[5] * sn + b1.y;
  v[6] = dn * acc[6] + (float)hv[6] * sn + b1.z;
  v[7] = dn * acc[7] + (float)hv[7] * sn + b1.w;
  size_t off = (size_t)n * D + c0;
  if (flags & 1) {
    float4 i0 = *(const float4*)&init_in[off];
    float4 i1 = *(const float4*)&init_in[off + 4];
    v[0] += i0.x; v[1] += i0.y; v[2] += i0.z; v[3] += i0.w;
    v[4] += i1.x; v[5] += i1.y; v[6] += i1.z; v[7] += i1.w;
  }
  if (flags & 2) {
    *(float4*)&init_out[off]     = make_float4(v[0], v[1], v[2], v[3]);
    *(float4*)&init_out[off + 4] = make_float4(v[4], v[5], v[6], v[7]);
  }
  if (flags & 4) {
    #pragma unroll
    for (int j = 0; j < 8; ++j) v[j] = fmaxf(v[j], 0.f);
  }
  if (flags & 8) {
    float4 p0 = *(const float4*)&out[off];
    float4 p1 = *(const float4*)&out[off + 4];
    v[0] += p0.x; v[1] += p0.y; v[2] += p0.z; v[3] += p0.w;
    v[4] += p1.x; v[5] += p1.y; v[6] += p1.z; v[7] += p1.w;
  }
  *(float4*)&out[off]     = make_float4(v[0], v[1], v[2], v[3]);
  *(float4*)&out[off + 4] = make_float4(v[4], v[5], v[6], v[7]);
  if (flags & 16) {
    f16x8 h8;
    #pragma unroll
    for (int j = 0; j < 8; ++j) h8[j] = (_Float16)v[j];
    *(f16x8*)&h16[off] = h8;
  }
}

// ---------------- launch ----------------

extern "C" void kernel_launch(void* const* d_in, const int* in_sizes, int n_in,
                              void* d_out, int out_size, void* d_ws, size_t ws_size,
                              hipStream_t stream) {
  const float* x = (const float*)d_in[0];
  const int* ei = (const int*)d_in[1];
  const float* Ws = (const float*)d_in[2];
  const float* bs = (const float*)d_in[3];
  float* out = (float*)d_out;

  const int N = in_sizes[0] / D;
  const int E = in_sizes[1] / 2;
  const int L = in_sizes[2] / (D * D);
  const int* src = ei;
  const int* dst = ei + E;

  uintptr_t p = (uintptr_t)d_ws;
  auto alloc = [&](size_t bytes) {
    uintptr_t r = p;
    p = (r + bytes + 255) & ~(uintptr_t)255;
    return r;
  };
  float*     dis      = (float*)alloc((size_t)N * 4);
  int*       counts   = (int*)  alloc((size_t)N * 4);
  int*       row_ptr  = (int*)  alloc((size_t)(N + 1) * 4);
  int*       fillp    = (int*)  alloc((size_t)N * 4);
  int*       blksum   = (int*)  alloc((size_t)1024 * 4);
  int2*      csr      = (int2*) alloc((size_t)E * 8);
  _Float16*  hw16     = (_Float16*)alloc((size_t)N * D * 2);
  _Float16*  h16      = (_Float16*)alloc((size_t)N * D * 2);  // also holds x16
  float*     init_buf = (float*)alloc((size_t)N * D * 4);
  _Float16*  Wf       = (_Float16*)alloc((size_t)L * 4 * 8 * 64 * 8 * 2);

  const int NB = (N + SCAN_CH - 1) / SCAN_CH;

  hipMemsetAsync(counts, 0, (size_t)N * 4, stream);
  hist_kernel<<<1024, 256, 0, stream>>>(dst, counts, E);
  dis_kernel<<<(N + 255) / 256, 256, 0, stream>>>(counts, dis, N);
  scan_phaseA<<<NB, 256, 0, stream>>>(counts, blksum, N);
  scan_phaseB<<<1, 1024, 0, stream>>>(blksum, NB);
  scan_phaseC<<<NB, 256, 0, stream>>>(counts, blksum, row_ptr, fillp, N);
  fill_kernel<<<1024, 256, 0, stream>>>(src, dst, dis, fillp, csr, E);
  conv_x_kernel<<<(N * D / 8 + 255) / 256, 256, 0, stream>>>(x, h16, N * D / 8);
  {
    int total = L * 2048;
    repack_w_kernel<<<(total + 255) / 256, 256, 0, stream>>>(Ws, Wf, total);
  }

  const int agg_grid = (N + 15) / 16;
  const int gemm_grid = (N + 63) / 64;

  for (int i = 0; i < L; ++i) {
    gemm16_kernel<<<gemm_grid, 256, 0, stream>>>(
        h16, (const f16x8*)(Wf + (size_t)i * 2048 * 8), hw16, N);
    int flags;
    if (i == 0)          flags = 4 | 16;
    else if (i == L - 1) flags = 1 | 4;
    else                 flags = 1 | 2 | 4 | 16;
    const float* init_in = (i <= 1) ? x : (const float*)init_buf;
    agg16_kernel<<<agg_grid, 256, 0, stream>>>(hw16, row_ptr, csr, dis,
        bs + (size_t)i * D, init_in, init_buf, out, h16, N, flags);
    if (i < L - 1) {
      int j = (i == 0) ? (L - 1) : (i - 1);
      gemm16_kernel<<<gemm_grid, 256, 0, stream>>>(
          h16, (const f16x8*)(Wf + (size_t)j * 2048 * 8), hw16, N);
      agg16_kernel<<<agg_grid, 256, 0, stream>>>(hw16, row_ptr, csr, dis,
          bs + (size_t)j * D, nullptr, nullptr, out, h16, N, 8 | 16);
    }
  }
}

// Round 5
// 1396.558 us; speedup vs baseline: 2.7665x; 1.1499x over previous
//
#include <hip/hip_runtime.h>

#define D 128
#define SCAN_CH 1024
#define SA_STRIDE 136   // fp16 units; 272B row: 16B-aligned, uniform LDS bank coverage
#define SC_STRIDE 132   // fp32 units; 528B row: 16B-aligned, 2-way-free on C writes

typedef _Float16 f16x8 __attribute__((ext_vector_type(8)));
typedef float f32x4 __attribute__((ext_vector_type(4)));

// ---------------- CSR build ----------------

__global__ void hist_kernel(const int* __restrict__ dst, int* __restrict__ counts, int E) {
  int stride = gridDim.x * blockDim.x;
  for (int e = blockIdx.x * blockDim.x + threadIdx.x; e < E; e += stride)
    atomicAdd(&counts[dst[e]], 1);
}

__global__ void dis_kernel(const int* __restrict__ counts, float* __restrict__ dis, int N) {
  int n = blockIdx.x * blockDim.x + threadIdx.x;
  if (n < N) dis[n] = rsqrtf((float)counts[n] + 1.0f);
}

__global__ __launch_bounds__(256) void scan_phaseA(const int* __restrict__ counts,
    int* __restrict__ blksum, int N) {
  __shared__ int red[256];
  int base = blockIdx.x * SCAN_CH;
  int t = threadIdx.x;
  int s = 0;
  #pragma unroll
  for (int j = 0; j < 4; ++j) {
    int idx = base + t * 4 + j;
    if (idx < N) s += counts[idx];
  }
  red[t] = s;
  __syncthreads();
  for (int d = 128; d > 0; d >>= 1) {
    if (t < d) red[t] += red[t + d];
    __syncthreads();
  }
  if (t == 0) blksum[blockIdx.x] = red[0];
}

__global__ __launch_bounds__(1024) void scan_phaseB(int* __restrict__ blksum, int NB) {
  __shared__ int sa[1024], sb[1024];
  int t = threadIdx.x;
  int v = (t < NB) ? blksum[t] : 0;
  sa[t] = v;
  __syncthreads();
  int* a = sa; int* b = sb;
  for (int d = 1; d < 1024; d <<= 1) {
    int val = a[t] + ((t >= d) ? a[t - d] : 0);
    b[t] = val;
    __syncthreads();
    int* tmp = a; a = b; b = tmp;
  }
  if (t < NB) blksum[t] = a[t] - v;  // exclusive
}

__global__ __launch_bounds__(256) void scan_phaseC(const int* __restrict__ counts,
    const int* __restrict__ blksum, int* __restrict__ row_ptr, int* __restrict__ fillp, int N) {
  __shared__ int ra[256], rb[256];
  int base = blockIdx.x * SCAN_CH;
  int t = threadIdx.x;
  int v[4]; int s = 0;
  #pragma unroll
  for (int j = 0; j < 4; ++j) {
    int idx = base + t * 4 + j;
    v[j] = (idx < N) ? counts[idx] : 0;
    s += v[j];
  }
  ra[t] = s;
  __syncthreads();
  int* a = ra; int* b = rb;
  for (int d = 1; d < 256; d <<= 1) {
    int val = a[t] + ((t >= d) ? a[t - d] : 0);
    b[t] = val;
    __syncthreads();
    int* tmp = a; a = b; b = tmp;
  }
  int excl = a[t] - s + blksum[blockIdx.x];
  #pragma unroll
  for (int j = 0; j < 4; ++j) {
    int idx = base + t * 4 + j;
    if (idx < N) {
      row_ptr[idx] = excl;
      fillp[idx] = excl;
      excl += v[j];
      if (idx == N - 1) row_ptr[N] = excl;
    }
  }
}

__global__ void fill_kernel(const int* __restrict__ src, const int* __restrict__ dst,
    int* __restrict__ fillp, int* __restrict__ csr_src, int E) {
  int stride = gridDim.x * blockDim.x;
  for (int e = blockIdx.x * blockDim.x + threadIdx.x; e < E; e += stride) {
    int s = src[e], d = dst[e];
    int p = atomicAdd(&fillp[d], 1);
    csr_src[p] = s;
  }
}

// ---------------- one-time conversions ----------------

// gather table hs0 = dis[n] * x[n]  (fp16)
__global__ void conv_x_kernel(const float* __restrict__ x, const float* __restrict__ dis,
    _Float16* __restrict__ hs, int total8) {
  int i = blockIdx.x * blockDim.x + threadIdx.x;
  if (i >= total8) return;
  int node = i >> 4;  // 16 chunks of 8 per 128-wide row
  float dn = dis[node];
  const float4* p = (const float4*)(x + (size_t)i * 8);
  float4 a = p[0], b = p[1];
  f16x8 v;
  v[0] = (_Float16)(dn * a.x); v[1] = (_Float16)(dn * a.y);
  v[2] = (_Float16)(dn * a.z); v[3] = (_Float16)(dn * a.w);
  v[4] = (_Float16)(dn * b.x); v[5] = (_Float16)(dn * b.y);
  v[6] = (_Float16)(dn * b.z); v[7] = (_Float16)(dn * b.w);
  *(f16x8*)(hs + (size_t)i * 8) = v;
}

// Wf layout: [L][kb(4)][nb(8)][lane(64)] of f16x8 (B fragment, K-slice 8)
__global__ void repack_w_kernel(const float* __restrict__ Ws, _Float16* __restrict__ Wf, int total) {
  int t = blockIdx.x * blockDim.x + threadIdx.x;
  if (t >= total) return;
  int lane = t & 63;
  int nb = (t >> 6) & 7;
  int kb = (t >> 9) & 3;
  int l = t >> 11;
  int col = nb * 16 + (lane & 15);
  int k0 = kb * 32 + (lane >> 4) * 8;
  const float* w = Ws + (size_t)l * D * D;
  f16x8 v;
  #pragma unroll
  for (int j = 0; j < 8; ++j) v[j] = (_Float16)w[(k0 + j) * D + col];
  *(f16x8*)(Wf + (size_t)t * 8) = v;
}

// ---------------- Fused conv: gather(hs_in) -> xW via MFMA -> epilogue ----------------
// agg_n = dis[n] * (sum_e hs_in[src_e] + hs_in[n]);  conv_n = agg_n @ W + b
// hs_in and hs_out are DISTINCT buffers (ping-pong) — same-buffer would race
// across workgroups (round-4 bug).
// flags: 1=add init_in, 2=write init_out, 4=relu, 8=out += val, 16=write hs_out
__global__ __launch_bounds__(256) void conv_fused_kernel(
    const _Float16* __restrict__ hs, const int* __restrict__ row_ptr,
    const int* __restrict__ csr_src, const float* __restrict__ dis,
    const f16x8* __restrict__ Wf, const float* __restrict__ bias,
    const float* __restrict__ init_in, float* __restrict__ init_out,
    float* __restrict__ out, _Float16* __restrict__ hs_out, int N, int flags) {
  __shared__ _Float16 sA[16 * SA_STRIDE];
  __shared__ float sC[16 * SC_STRIDE];
  int tid = threadIdx.x;
  int node0 = blockIdx.x * 16;
  int ng = tid >> 4;
  int li = tid & 15;
  int n = node0 + ng;

  // ---- gather phase: one node per 16-lane group ----
  {
    float acc[8];
    #pragma unroll
    for (int j = 0; j < 8; ++j) acc[j] = 0.f;
    f16x8 g = {};
    if (n < N) {
      int beg = row_ptr[n], end = row_ptr[n + 1];
      int c0 = li * 8;
      #pragma unroll 4
      for (int e = beg; e < end; ++e) {
        int s = csr_src[e];
        f16x8 v = *(const f16x8*)&hs[(size_t)s * D + c0];
        #pragma unroll
        for (int j = 0; j < 8; ++j) acc[j] += (float)v[j];
      }
      f16x8 own = *(const f16x8*)&hs[(size_t)n * D + c0];
      float dn = dis[n];
      #pragma unroll
      for (int j = 0; j < 8; ++j) g[j] = (_Float16)(dn * (acc[j] + (float)own[j]));
    }
    *(f16x8*)&sA[ng * SA_STRIDE + li * 8] = g;
  }

  // ---- B fragments (wave w covers cols [32w, 32w+32)) ----
  int wave = tid >> 6, lane = tid & 63;
  f16x8 bf[4][2];
  #pragma unroll
  for (int kb = 0; kb < 4; ++kb)
    #pragma unroll
    for (int i = 0; i < 2; ++i)
      bf[kb][i] = Wf[(kb * 8 + wave * 2 + i) * 64 + lane];
  __syncthreads();

  // ---- MFMA: A = sA rows (16 nodes x 128), per wave 2 col-blocks ----
  f32x4 ca = {0.f, 0.f, 0.f, 0.f}, cb = {0.f, 0.f, 0.f, 0.f};
  #pragma unroll
  for (int kb = 0; kb < 4; ++kb) {
    f16x8 a = *(const f16x8*)&sA[(lane & 15) * SA_STRIDE + kb * 32 + (lane >> 4) * 8];
    ca = __builtin_amdgcn_mfma_f32_16x16x32_f16(a, bf[kb][0], ca, 0, 0, 0);
    cb = __builtin_amdgcn_mfma_f32_16x16x32_f16(a, bf[kb][1], cb, 0, 0, 0);
  }

  // ---- stage C ----
  {
    int colb = wave * 32 + (lane & 15);
    int rowb = (lane >> 4) * 4;
    #pragma unroll
    for (int r = 0; r < 4; ++r) {
      sC[(rowb + r) * SC_STRIDE + colb]      = ca[r];
      sC[(rowb + r) * SC_STRIDE + colb + 16] = cb[r];
    }
  }
  __syncthreads();

  // ---- epilogue: per thread 8 features of one node ----
  if (n >= N) return;
  {
    int c0 = li * 8;
    float v[8];
    float4 s0 = *(const float4*)&sC[ng * SC_STRIDE + c0];
    float4 s1 = *(const float4*)&sC[ng * SC_STRIDE + c0 + 4];
    float4 b0 = *(const float4*)&bias[c0];
    float4 b1 = *(const float4*)&bias[c0 + 4];
    v[0] = s0.x + b0.x; v[1] = s0.y + b0.y; v[2] = s0.z + b0.z; v[3] = s0.w + b0.w;
    v[4] = s1.x + b1.x; v[5] = s1.y + b1.y; v[6] = s1.z + b1.z; v[7] = s1.w + b1.w;
    size_t off = (size_t)n * D + c0;
    if (flags & 1) {
      float4 i0 = *(const float4*)&init_in[off];
      float4 i1 = *(const float4*)&init_in[off + 4];
      v[0] += i0.x; v[1] += i0.y; v[2] += i0.z; v[3] += i0.w;
      v[4] += i1.x; v[5] += i1.y; v[6] += i1.z; v[7] += i1.w;
    }
    if (flags & 2) {
      *(float4*)&init_out[off]     = make_float4(v[0], v[1], v[2], v[3]);
      *(float4*)&init_out[off + 4] = make_float4(v[4], v[5], v[6], v[7]);
    }
    if (flags & 4) {
      #pragma unroll
      for (int j = 0; j < 8; ++j) v[j] = fmaxf(v[j], 0.f);
    }
    if (flags & 8) {
      float4 p0 = *(const float4*)&out[off];
      float4 p1 = *(const float4*)&out[off + 4];
      v[0] += p0.x; v[1] += p0.y; v[2] += p0.z; v[3] += p0.w;
      v[4] += p1.x; v[5] += p1.y; v[6] += p1.z; v[7] += p1.w;
    }
    *(float4*)&out[off]     = make_float4(v[0], v[1], v[2], v[3]);
    *(float4*)&out[off + 4] = make_float4(v[4], v[5], v[6], v[7]);
    if (flags & 16) {
      float dn = dis[n];
      f16x8 h8;
      #pragma unroll
      for (int j = 0; j < 8; ++j) h8[j] = (_Float16)(dn * v[j]);
      *(f16x8*)&hs_out[off] = h8;
    }
  }
}

// ---------------- launch ----------------

extern "C" void kernel_launch(void* const* d_in, const int* in_sizes, int n_in,
                              void* d_out, int out_size, void* d_ws, size_t ws_size,
                              hipStream_t stream) {
  const float* x = (const float*)d_in[0];
  const int* ei = (const int*)d_in[1];
  const float* Ws = (const float*)d_in[2];
  const float* bs = (const float*)d_in[3];
  float* out = (float*)d_out;

  const int N = in_sizes[0] / D;
  const int E = in_sizes[1] / 2;
  const int L = in_sizes[2] / (D * D);
  const int* src = ei;
  const int* dst = ei + E;

  uintptr_t p = (uintptr_t)d_ws;
  auto alloc = [&](size_t bytes) {
    uintptr_t r = p;
    p = (r + bytes + 255) & ~(uintptr_t)255;
    return r;
  };
  float*     dis      = (float*)alloc((size_t)N * 4);
  int*       counts   = (int*)  alloc((size_t)N * 4);
  int*       row_ptr  = (int*)  alloc((size_t)(N + 1) * 4);
  int*       fillp    = (int*)  alloc((size_t)N * 4);
  int*       blksum   = (int*)  alloc((size_t)1024 * 4);
  int*       csr_src  = (int*)  alloc((size_t)E * 4);
  _Float16*  hs_a     = (_Float16*)alloc((size_t)N * D * 2);  // ping
  _Float16*  hs_b     = (_Float16*)alloc((size_t)N * D * 2);  // pong
  float*     init_buf = (float*)alloc((size_t)N * D * 4);
  _Float16*  Wf       = (_Float16*)alloc((size_t)L * 4 * 8 * 64 * 8 * 2);

  const int NB = (N + SCAN_CH - 1) / SCAN_CH;

  hipMemsetAsync(counts, 0, (size_t)N * 4, stream);
  hist_kernel<<<1024, 256, 0, stream>>>(dst, counts, E);
  dis_kernel<<<(N + 255) / 256, 256, 0, stream>>>(counts, dis, N);
  scan_phaseA<<<NB, 256, 0, stream>>>(counts, blksum, N);
  scan_phaseB<<<1, 1024, 0, stream>>>(blksum, NB);
  scan_phaseC<<<NB, 256, 0, stream>>>(counts, blksum, row_ptr, fillp, N);
  fill_kernel<<<1024, 256, 0, stream>>>(src, dst, fillp, csr_src, E);
  conv_x_kernel<<<(N * 16 + 255) / 256, 256, 0, stream>>>(x, dis, hs_a, N * 16);
  {
    int total = L * 2048;
    repack_w_kernel<<<(total + 255) / 256, 256, 0, stream>>>(Ws, Wf, total);
  }

  const int conv_grid = (N + 15) / 16;
  _Float16* hsp[2] = {hs_a, hs_b};
  int cur = 0;

  for (int i = 0; i < L; ++i) {
    int flags;
    if (i == 0)          flags = 4 | 16;
    else if (i == L - 1) flags = 1 | 4;
    else                 flags = 1 | 2 | 4 | 16;
    const float* init_in = (i <= 1) ? x : (const float*)init_buf;
    conv_fused_kernel<<<conv_grid, 256, 0, stream>>>(hsp[cur], row_ptr, csr_src, dis,
        (const f16x8*)(Wf + (size_t)i * 2048 * 8), bs + (size_t)i * D,
        init_in, init_buf, out, hsp[cur ^ 1], N, flags);
    if (flags & 16) cur ^= 1;
    if (i < L - 1) {
      int j = (i == 0) ? (L - 1) : (i - 1);
      conv_fused_kernel<<<conv_grid, 256, 0, stream>>>(hsp[cur], row_ptr, csr_src, dis,
          (const f16x8*)(Wf + (size_t)j * 2048 * 8), bs + (size_t)j * D,
          nullptr, nullptr, out, hsp[cur ^ 1], N, 8 | 16);
      cur ^= 1;
    }
  }
}